// Round 11
// baseline (355.927 us; speedup 1.0000x reference)
//
#include <hip/hip_runtime.h>
#include <cstddef>

// Problem constants
#define NMOD   8
#define DEPTH_ 2
#define DIME   128
#define CCH    128   // channels
#define HH     32
#define WW     32
#define BB     16
#define HWPX   (HH*WW)

// Conv: zero-LDS direct-global design. Per block: 4 co x 64 ci, 256 threads,
// no __shared__ at all -> no bank conflicts, no main-loop barriers.
// Edges via zero-page pointer redirection (step 0). 1024 blocks, 4/CU.
#define CO_TILE 4
#define CI_HALF 64

// ---------------------------------------------------------------------------
// Pool: pooled[b,c] = mean(x[b,c,:,:]). Also zeroes the conv zero-page.
// ---------------------------------------------------------------------------
__global__ __launch_bounds__(256) void pool_kernel(
    const float* __restrict__ x, float* __restrict__ pooled,
    float* __restrict__ zpage)
{
    if (blockIdx.x == 0 && threadIdx.x < 64) zpage[threadIdx.x] = 0.f;

    const int ch   = blockIdx.x * 4 + (threadIdx.x >> 6);   // 0..2047 = b*128+c
    const int lane = threadIdx.x & 63;
    const float* xc = x + (size_t)ch * HWPX;

    float4 s4 = {0.f, 0.f, 0.f, 0.f};
    #pragma unroll
    for (int k = 0; k < 4; ++k) {
        const float4 v = *(const float4*)(xc + (size_t)(lane + k * 64) * 4);
        s4.x += v.x; s4.y += v.y; s4.z += v.z; s4.w += v.w;
    }
    float s = (s4.x + s4.y) + (s4.z + s4.w);
    #pragma unroll
    for (int off = 32; off; off >>= 1) s += __shfl_xor(s, off, 64);
    if (lane == 0) pooled[ch] = s * (1.0f / HWPX);
}

// ---------------------------------------------------------------------------
// Ctl: ctl = pooled @ W_ctl^T + b_ctl ; d2/argmin vs emb ; ctl_nearest.
// ---------------------------------------------------------------------------
__global__ __launch_bounds__(256) void ctl_kernel(
    const float* __restrict__ pooled, const float* __restrict__ W_ctl,
    const float* __restrict__ b_ctl, const float* __restrict__ emb,
    float* __restrict__ ctl_out, float* __restrict__ ctln_out,
    int* __restrict__ idx_out)
{
    const int b   = blockIdx.x;
    const int tid = threadIdx.x;

    __shared__ float pld[CCH];
    __shared__ float ctlrow[DIME * DEPTH_];
    __shared__ float d2s[DEPTH_ * NMOD];
    __shared__ int   sidx[DEPTH_];

    if (tid < CCH / 4)
        ((float4*)pld)[tid] = ((const float4*)(pooled + (size_t)b * CCH))[tid];
    __syncthreads();

    // ctl[j] = pooled . W_ctl[j,:] + b_ctl[j]; 32 independent float4 loads
    {
        const float4* wr = (const float4*)(W_ctl + (size_t)tid * CCH);
        const float4* pv = (const float4*)pld;
        float a0 = 0.f, a1 = 0.f, a2 = 0.f, a3 = 0.f;
        #pragma unroll
        for (int k = 0; k < 32; k += 4) {
            const float4 w0 = wr[k + 0], p0 = pv[k + 0];
            const float4 w1 = wr[k + 1], p1 = pv[k + 1];
            const float4 w2 = wr[k + 2], p2 = pv[k + 2];
            const float4 w3 = wr[k + 3], p3 = pv[k + 3];
            a0 = fmaf(w0.x, p0.x, fmaf(w0.y, p0.y, fmaf(w0.z, p0.z, fmaf(w0.w, p0.w, a0))));
            a1 = fmaf(w1.x, p1.x, fmaf(w1.y, p1.y, fmaf(w1.z, p1.z, fmaf(w1.w, p1.w, a1))));
            a2 = fmaf(w2.x, p2.x, fmaf(w2.y, p2.y, fmaf(w2.z, p2.z, fmaf(w2.w, p2.w, a2))));
            a3 = fmaf(w3.x, p3.x, fmaf(w3.y, p3.y, fmaf(w3.z, p3.z, fmaf(w3.w, p3.w, a3))));
        }
        const float s = b_ctl[tid] + ((a0 + a1) + (a2 + a3));
        ctlrow[tid] = s;
        ctl_out[(size_t)b * (DIME * DEPTH_) + tid] = s;
    }
    __syncthreads();

    // d2[t][m]: 16 (t,m) pairs x 16 lanes, each lane sums 8 e's, shfl-reduce
    {
        const int p = tid >> 4;          // 0..15 -> (t,m)
        const int sub = tid & 15;
        const int t = p >> 3, mm = p & 7;
        float s = 0.f;
        #pragma unroll
        for (int k = 0; k < 8; ++k) {
            const int e = sub * 8 + k;
            const float d = ctlrow[e * DEPTH_ + t] - emb[e * NMOD + mm];
            s = fmaf(d, d, s);
        }
        #pragma unroll
        for (int off = 8; off; off >>= 1) s += __shfl_xor(s, off, 16);
        if (sub == 0) d2s[p] = s;
    }
    __syncthreads();

    // argmin over m (first-min tie-break, matching jnp.argmin)
    if (tid < DEPTH_) {
        float best = d2s[tid * NMOD];
        int bi = 0;
        for (int m = 1; m < NMOD; ++m) {
            const float d = d2s[tid * NMOD + m];
            if (d < best) { best = d; bi = m; }
        }
        sidx[tid] = bi;
        idx_out[b * DEPTH_ + tid] = bi;
    }
    __syncthreads();

    // ctl_nearest[b,e,t] = emb[e, idx[b,t]]
    {
        const int e = tid >> 1, t = tid & 1;
        ctln_out[(size_t)b * (DIME * DEPTH_) + e * DEPTH_ + t] =
            emb[e * NMOD + sidx[t]];
    }
}

// ---------------------------------------------------------------------------
// Conv partial, zero-LDS: block (cog, b, z) sums ci in [z*64, z*64+64) for
// 4 output channels. Each thread owns 4 px, reads its 3x6 input window
// straight from global (L2-resident, 256KB/block working set). SAME-pad
// edges via zero-page redirected pointers (step 0). Weights via uniform
// scalar loads (SGPR). Raw partial sums to p0 (z=0) / p1 (z=1).
// ---------------------------------------------------------------------------
__global__ __launch_bounds__(256, 4) void conv_kernel(
    const float* __restrict__ in, const float* __restrict__ W_exp,
    const int* __restrict__ idx, int t, const float* __restrict__ zpage,
    float* __restrict__ p0, float* __restrict__ p1)
{
    const int cog  = blockIdx.x;           // 0..31
    const int b    = blockIdx.y;           // 0..15
    const int half = blockIdx.z;           // 0..1 (ci range)
    const int tid  = threadIdx.x;
    const int ci_base = half * CI_HALF;
    const int m   = __builtin_amdgcn_readfirstlane(idx[b * DEPTH_ + t]);
    const int co0 = cog * CO_TILE;

    // Uniform per-co weight bases (ci-run contiguous, 9 floats per ci)
    const float* wb = W_exp + (size_t)m * CCH * (CCH * 9) + (size_t)ci_base * 9;
    const float* wc0 = wb + (size_t)(co0 + 0) * (CCH * 9);
    const float* wc1 = wb + (size_t)(co0 + 1) * (CCH * 9);
    const float* wc2 = wb + (size_t)(co0 + 2) * (CCH * 9);
    const float* wc3 = wb + (size_t)(co0 + 3) * (CCH * 9);

    const int h  = tid >> 3;               // 0..31
    const int wp = tid & 7;                // 0..7
    const int w4 = wp * 4;                 // 0,4,...,28

    // Per-row window pointers: main (4 aligned), left col, right col.
    // Invalid row/col -> zero-page with step 0.
    const float* xb = in + (size_t)b * CCH * HWPX + (size_t)ci_base * HWPX;
    const float* pm[3]; const float* pl[3]; const float* pr[3];
    int sm[3], sl[3], sr[3];
    #pragma unroll
    for (int kh = 0; kh < 3; ++kh) {
        const int row = h + kh - 1;
        const bool vr = (unsigned)row < 32u;
        const float* rbase = xb + row * WW;
        const bool vl = vr && (wp > 0);
        const bool vR = vr && (wp < 7);
        pm[kh] = vr ? (rbase + w4)     : zpage;  sm[kh] = vr ? HWPX : 0;
        pl[kh] = vl ? (rbase + w4 - 1) : zpage;  sl[kh] = vl ? HWPX : 0;
        pr[kh] = vR ? (rbase + w4 + 4) : zpage;  sr[kh] = vR ? HWPX : 0;
    }

    float acc[4][CO_TILE];
    #pragma unroll
    for (int p = 0; p < 4; ++p)
        #pragma unroll
        for (int c = 0; c < CO_TILE; ++c) acc[p][c] = 0.f;

    // Current-iteration window registers (prefetch chunk 0)
    float4 cm[3]; float cl[3], cr[3];
    #pragma unroll
    for (int kh = 0; kh < 3; ++kh) {
        cm[kh] = *(const float4*)pm[kh];
        cl[kh] = *pl[kh];
        cr[kh] = *pr[kh];
    }

    // FMA body for one ci (weights via uniform scalar loads)
    auto body = [&](int ci) {
        const int cw = ci * 9;
        float wr[CO_TILE][9];
        #pragma unroll
        for (int j = 0; j < 9; ++j) {
            wr[0][j] = wc0[cw + j];
            wr[1][j] = wc1[cw + j];
            wr[2][j] = wc2[cw + j];
            wr[3][j] = wc3[cw + j];
        }
        #pragma unroll
        for (int kh = 0; kh < 3; ++kh) {
            const float in6[6] = {cl[kh], cm[kh].x, cm[kh].y, cm[kh].z,
                                  cm[kh].w, cr[kh]};
            #pragma unroll
            for (int kw = 0; kw < 3; ++kw) {
                #pragma unroll
                for (int p = 0; p < 4; ++p) {
                    const float v = in6[p + kw];
                    acc[p][0] = fmaf(v, wr[0][kh * 3 + kw], acc[p][0]);
                    acc[p][1] = fmaf(v, wr[1][kh * 3 + kw], acc[p][1]);
                    acc[p][2] = fmaf(v, wr[2][kh * 3 + kw], acc[p][2]);
                    acc[p][3] = fmaf(v, wr[3][kh * 3 + kw], acc[p][3]);
                }
            }
        }
    };

    // Main loop: prefetch ci+1 while computing ci (no barriers anywhere)
    for (int ci = 0; ci < CI_HALF - 1; ++ci) {
        float4 nm[3]; float nl[3], nr[3];
        #pragma unroll
        for (int kh = 0; kh < 3; ++kh) {
            pm[kh] += sm[kh]; pl[kh] += sl[kh]; pr[kh] += sr[kh];
            nm[kh] = *(const float4*)pm[kh];
            nl[kh] = *pl[kh];
            nr[kh] = *pr[kh];
        }
        body(ci);
        #pragma unroll
        for (int kh = 0; kh < 3; ++kh) {
            cm[kh] = nm[kh]; cl[kh] = nl[kh]; cr[kh] = nr[kh];
        }
    }
    body(CI_HALF - 1);   // epilogue (no prefetch past the half)

    // Raw partial sums, coalesced float4 stores
    float* outp = (half == 0) ? p0 : p1;
    float* ob = outp + ((size_t)b * CCH + co0) * HWPX + h * WW + w4;
    #pragma unroll
    for (int c = 0; c < CO_TILE; ++c) {
        float4 v;
        v.x = acc[0][c]; v.y = acc[1][c]; v.z = acc[2][c]; v.w = acc[3][c];
        *(float4*)(ob + (size_t)c * HWPX) = v;
    }
}

// ---------------------------------------------------------------------------
// Combine: out = relu(p0 + p1 + bias). Elementwise float4; outp may alias
// p0 or p1 (same-index read/write is safe).
// ---------------------------------------------------------------------------
__global__ __launch_bounds__(256) void combine_kernel(
    const float* __restrict__ p0, const float* __restrict__ p1,
    const float* __restrict__ b_exp, const int* __restrict__ idx, int t,
    float* __restrict__ outp)
{
    const int i4 = blockIdx.x * 256 + threadIdx.x;   // float4 index
    const int b  = i4 >> 15;                         // 32768 float4 per batch
    const int co = (i4 >> 8) & (CCH - 1);            // 256 float4 per channel
    const int m  = idx[b * DEPTH_ + t];
    const float bv = b_exp[m * CCH + co];
    const float4 a = ((const float4*)p0)[i4];
    const float4 c = ((const float4*)p1)[i4];
    float4 v;
    v.x = fmaxf(a.x + c.x + bv, 0.f);
    v.y = fmaxf(a.y + c.y + bv, 0.f);
    v.z = fmaxf(a.z + c.z + bv, 0.f);
    v.w = fmaxf(a.w + c.w + bv, 0.f);
    ((float4*)outp)[i4] = v;
}

// ---------------------------------------------------------------------------
extern "C" void kernel_launch(void* const* d_in, const int* in_sizes, int n_in,
                              void* d_out, int out_size, void* d_ws, size_t ws_size,
                              hipStream_t stream) {
    const float* x     = (const float*)d_in[0];
    const float* W_ctl = (const float*)d_in[1];
    const float* b_ctl = (const float*)d_in[2];
    const float* emb   = (const float*)d_in[3];
    const float* W_exp = (const float*)d_in[4];
    const float* b_exp = (const float*)d_in[5];

    float* out      = (float*)d_out;
    float* y_out    = out;                                      // (16,128,32,32)
    float* ctl_out  = out + (size_t)BB * CCH * HWPX;            // (16,128,2)
    float* ctln_out = ctl_out + BB * DIME * DEPTH_;             // (16,128,2)

    // ws layout: wsA (8.4MB) | idx (128B) | pooled (8KB) | zpage (256B)
    float* wsA    = (float*)d_ws;
    int*   idxp   = (int*)((char*)d_ws + (size_t)BB * CCH * HWPX * sizeof(float));
    float* pooled = (float*)((char*)idxp + 128);
    float* zpage  = pooled + BB * CCH;                          // 64 floats used
    float* xbuf   = (float*)d_in[0];   // clobbered in L2 (harness restores)

    const int NY4 = (BB * CCH * HWPX) / 4;                      // 524288 float4

    pool_kernel<<<(BB * CCH) / 4, 256, 0, stream>>>(x, pooled, zpage);
    ctl_kernel<<<BB, 256, 0, stream>>>(pooled, W_ctl, b_ctl, emb,
                                       ctl_out, ctln_out, idxp);

    // Layer 1: partials p0 -> y_out region (scratch until final), p1 -> wsA
    conv_kernel<<<dim3(CCH / CO_TILE, BB, 2), 256, 0, stream>>>(
        x, W_exp, idxp, 0, zpage, y_out, wsA);
    // y1 = relu(p0+p1+b) -> wsA (in-place on p1)
    combine_kernel<<<NY4 / 256, 256, 0, stream>>>(
        y_out, wsA, b_exp, idxp, 0, wsA);

    // Layer 2: partials p0 -> y_out region, p1 -> xbuf (x dead after L1)
    conv_kernel<<<dim3(CCH / CO_TILE, BB, 2), 256, 0, stream>>>(
        wsA, W_exp, idxp, 1, zpage, y_out, xbuf);
    // final y = relu(p0+p1+b) -> y_out (in-place on p0)
    combine_kernel<<<NY4 / 256, 256, 0, stream>>>(
        y_out, xbuf, b_exp, idxp, 1, y_out);
}